// Round 3
// baseline (138.200 us; speedup 1.0000x reference)
//
#include <hip/hip_runtime.h>
#include <cmath>

#define TABLE_NUM 16
#define T_SIZE    4096
#define Z_DIM     512
#define IMG       256
#define D_TAB     (TABLE_NUM * T_SIZE * 2)       // 131072
#define BATCH     8
#define HID       64
#define N_PIX     (IMG * IMG)                    // 65536
#define PRIME_Y   2654435761u
#define L_STAGE   13                             // levels 13,14,15 staged in LDS
#define PPB       1024                           // pixels per block
#define ITERS     (PPB / 256)

typedef _Float16 v8h  __attribute__((ext_vector_type(8)));
typedef _Float16 v2h  __attribute__((ext_vector_type(2)));
typedef float    v4f  __attribute__((ext_vector_type(4)));

struct ResArr { float r[TABLE_NUM]; };

// ---------------------------------------------------------------------------
// Kernel 1: tables[b][n] = sum_k z[b][k] * w_table[k][n] + b_table[n]
// (unchanged from R2 — isolating the hash_mlp delta this round)
// ---------------------------------------------------------------------------
__global__ __launch_bounds__(256) void gen_tables(
    const float* __restrict__ z, const float* __restrict__ w,
    const float* __restrict__ bt, float* __restrict__ tabs)
{
    const int n0 = (blockIdx.x * 256 + threadIdx.x) * 2;
    const float2* wp = reinterpret_cast<const float2*>(w) + (n0 >> 1);

    float acc[BATCH][2];
#pragma unroll
    for (int b = 0; b < BATCH; ++b) { acc[b][0] = 0.f; acc[b][1] = 0.f; }

#pragma unroll 16
    for (int k = 0; k < Z_DIM; ++k) {
        float2 wv = wp[(size_t)k * (D_TAB / 2)];
#pragma unroll
        for (int b = 0; b < BATCH; ++b) {
            float zv = z[b * Z_DIM + k];       // uniform -> s_load
            acc[b][0] = fmaf(zv, wv.x, acc[b][0]);
            acc[b][1] = fmaf(zv, wv.y, acc[b][1]);
        }
    }

    float2 bv = reinterpret_cast<const float2*>(bt)[n0 >> 1];
#pragma unroll
    for (int b = 0; b < BATCH; ++b) {
        float2 o;
        o.x = acc[b][0] + bv.x;
        o.y = acc[b][1] + bv.y;
        reinterpret_cast<float2*>(tabs)[(size_t)b * (D_TAB / 2) + (n0 >> 1)] = o;
    }
}

// ---------------------------------------------------------------------------
// Kernel 2: fused hash-grid + MFMA MLP, 1024 pixels/block.
// - Levels 13..15 (finest; ~45% of divergent L1 line lookups) staged in LDS,
//   gathered via ds_read_b64 (random-bank ~2x floor ~= 10 cyc vs ~64 L1 cyc).
// - MLP weights f16-converted into LDS per block (stride-72 rows: 144 B = 9*16
//   -> all v8h reads 16B-aligned, b128 reads at the 8-lane/bank-quad floor).
// - mbuf is per-wave: no inter-layer __syncthreads needed (within-wave lgkmcnt
//   ordering is compiler-inserted). Single barrier after staging.
// - LDS 147.3 KB -> 1 block/CU; full unroll of coarse levels for load ILP.
// ---------------------------------------------------------------------------
__global__ __launch_bounds__(256, 1) void hash_mlp(
    const float* __restrict__ tabs,
    const float* __restrict__ w1, const float* __restrict__ b1,
    const float* __restrict__ w2, const float* __restrict__ b2,
    const float* __restrict__ w3, const float* __restrict__ b3,
    float* __restrict__ out, ResArr res)
{
    __shared__ float2   tstage[3][T_SIZE];     // 96 KB   (levels 13,14,15, f32)
    __shared__ _Float16 mbuf[4][64][72];       // 36.9 KB (per-wave redistribution)
    __shared__ _Float16 w1T[HID][32];          // 4 KB
    __shared__ _Float16 w2T[HID][72];          // 9.2 KB (cols 0..63 used)
    __shared__ _Float16 w3T[16][72];           // 2.25 KB

    const int tid  = threadIdx.x;
    const int wid  = tid >> 6;
    const int lane = tid & 63;
    const int b    = blockIdx.x & 7;           // batch == XCD (round-robin)
    const int tile = blockIdx.x >> 3;          // 0..63
    const float* tb = tabs + (size_t)b * D_TAB;
    const float2* tb2 = reinterpret_cast<const float2*>(tb);

    // ---- stage weights (f32 -> f16, transposed to [n][k]) ----
    for (int i = tid; i < 32 * HID; i += 256) {          // w1 (32,64)
        int k = i >> 6, n = i & 63;
        w1T[n][k] = (_Float16)w1[i];
    }
    for (int i = tid; i < HID * HID; i += 256) {         // w2 (64,64)
        int k = i >> 6, n = i & 63;
        w2T[n][k] = (_Float16)w2[i];
    }
    for (int i = tid; i < 16 * HID; i += 256) {          // w3 (64,3) pad to 16
        int n = i >> 6, k = i & 63;
        w3T[n][k] = (_Float16)(n < 3 ? w3[k * 3 + n] : 0.f);
    }
    // ---- stage fine-level tables ----
    for (int i = tid; i < 3 * T_SIZE; i += 256) {
        int l = i >> 12, e = i & (T_SIZE - 1);
        tstage[l][e] = tb2[(L_STAGE + l) * T_SIZE + e];
    }
    __syncthreads();

    const int arow = lane & 15;        // A row / B col / C col
    const int kgrp = lane >> 4;        // k-group

    // hoisted, iteration-invariant: biases + all B-fragments (LDS reads once)
    float bias1v[4], bias2v[4];
#pragma unroll
    for (int nt = 0; nt < 4; ++nt) {
        bias1v[nt] = b1[nt * 16 + arow];
        bias2v[nt] = b2[nt * 16 + arow];
    }
    const float bias3 = (arow < 3) ? b3[arow] : 0.f;

    v8h bf1[4], bf2a[4], bf2b[4];
#pragma unroll
    for (int nt = 0; nt < 4; ++nt) {
        bf1[nt]  = *reinterpret_cast<const v8h*>(&w1T[nt * 16 + arow][kgrp * 8]);
        bf2a[nt] = *reinterpret_cast<const v8h*>(&w2T[nt * 16 + arow][kgrp * 8]);
        bf2b[nt] = *reinterpret_cast<const v8h*>(&w2T[nt * 16 + arow][32 + kgrp * 8]);
    }
    v8h bf3a = *reinterpret_cast<const v8h*>(&w3T[arow][kgrp * 8]);
    v8h bf3b = *reinterpret_cast<const v8h*>(&w3T[arow][32 + kgrp * 8]);

    for (int it = 0; it < ITERS; ++it) {
        const int n = tile * PPB + it * 256 + tid;     // this thread's pixel
        const float cx = ((float)(n >> 8)  + 0.5f) * (1.0f / IMG);
        const float cy = ((float)(n & 255) + 0.5f) * (1.0f / IMG);

        // ---- coarse levels 0..12: gather from global (L1/L2) ----
#pragma unroll
        for (int l = 0; l < L_STAGE; ++l) {
            float r  = res.r[l];
            float px = cx * r, py = cy * r;
            float fx0 = floorf(px), fy0 = floorf(py);
            float fx = px - fx0, fy = py - fy0;
            unsigned x0 = (unsigned)(int)fx0, y0 = (unsigned)(int)fy0;
            unsigned hy0 = y0 * PRIME_Y, hy1 = (y0 + 1u) * PRIME_Y;
            unsigned i00 = (x0 ^ hy0) & (T_SIZE - 1);
            unsigned i10 = ((x0 + 1u) ^ hy0) & (T_SIZE - 1);
            unsigned i01 = (x0 ^ hy1) & (T_SIZE - 1);
            unsigned i11 = ((x0 + 1u) ^ hy1) & (T_SIZE - 1);
            const float2* tl = tb2 + l * T_SIZE;
            float2 f00 = tl[i00], f10 = tl[i10], f01 = tl[i01], f11 = tl[i11];
            float w00 = (1.f - fx) * (1.f - fy);
            float w10 = fx * (1.f - fy);
            float w01 = (1.f - fx) * fy;
            float w11 = fx * fy;
            float e0 = f00.x * w00 + f10.x * w10 + f01.x * w01 + f11.x * w11;
            float e1 = f00.y * w00 + f10.y * w10 + f01.y * w01 + f11.y * w11;
            v2h p; p.x = (_Float16)e0; p.y = (_Float16)e1;
            *reinterpret_cast<v2h*>(&mbuf[wid][lane][2 * l]) = p;
        }
        // ---- fine levels 13..15: gather from LDS ----
#pragma unroll
        for (int l = L_STAGE; l < TABLE_NUM; ++l) {
            float r  = res.r[l];
            float px = cx * r, py = cy * r;
            float fx0 = floorf(px), fy0 = floorf(py);
            float fx = px - fx0, fy = py - fy0;
            unsigned x0 = (unsigned)(int)fx0, y0 = (unsigned)(int)fy0;
            unsigned hy0 = y0 * PRIME_Y, hy1 = (y0 + 1u) * PRIME_Y;
            unsigned i00 = (x0 ^ hy0) & (T_SIZE - 1);
            unsigned i10 = ((x0 + 1u) ^ hy0) & (T_SIZE - 1);
            unsigned i01 = (x0 ^ hy1) & (T_SIZE - 1);
            unsigned i11 = ((x0 + 1u) ^ hy1) & (T_SIZE - 1);
            const float2* tl = tstage[l - L_STAGE];
            float2 f00 = tl[i00], f10 = tl[i10], f01 = tl[i01], f11 = tl[i11];
            float w00 = (1.f - fx) * (1.f - fy);
            float w10 = fx * (1.f - fy);
            float w01 = (1.f - fx) * fy;
            float w11 = fx * fy;
            float e0 = f00.x * w00 + f10.x * w10 + f01.x * w01 + f11.x * w11;
            float e1 = f00.y * w00 + f10.y * w10 + f01.y * w01 + f11.y * w11;
            v2h p; p.x = (_Float16)e0; p.y = (_Float16)e1;
            *reinterpret_cast<v2h*>(&mbuf[wid][lane][2 * l]) = p;
        }

        // ---- layer 1: 32 -> 64 ----
        v8h a1[4];
#pragma unroll
        for (int mt = 0; mt < 4; ++mt)
            a1[mt] = *reinterpret_cast<const v8h*>(&mbuf[wid][mt * 16 + arow][kgrp * 8]);

        v4f c1[4][4];
#pragma unroll
        for (int nt = 0; nt < 4; ++nt)
#pragma unroll
            for (int mt = 0; mt < 4; ++mt) {
                v4f c = {0.f, 0.f, 0.f, 0.f};
                c = __builtin_amdgcn_mfma_f32_16x16x32_f16(a1[mt], bf1[nt], c, 0, 0, 0);
#pragma unroll
                for (int e = 0; e < 4; ++e)
                    c1[mt][nt][e] = fmaxf(c[e] + bias1v[nt], 0.f);
            }

        // write h1 (rows=pixel, cols=hidden); within-wave RAW/WAR ordering only
#pragma unroll
        for (int mt = 0; mt < 4; ++mt)
#pragma unroll
            for (int nt = 0; nt < 4; ++nt)
#pragma unroll
                for (int e = 0; e < 4; ++e)
                    mbuf[wid][mt * 16 + kgrp * 4 + e][nt * 16 + arow] = (_Float16)c1[mt][nt][e];

        // ---- layer 2: 64 -> 64 ----
        v8h a2[4][2];
#pragma unroll
        for (int mt = 0; mt < 4; ++mt) {
            a2[mt][0] = *reinterpret_cast<const v8h*>(&mbuf[wid][mt * 16 + arow][kgrp * 8]);
            a2[mt][1] = *reinterpret_cast<const v8h*>(&mbuf[wid][mt * 16 + arow][32 + kgrp * 8]);
        }
        v4f c2[4][4];
#pragma unroll
        for (int nt = 0; nt < 4; ++nt)
#pragma unroll
            for (int mt = 0; mt < 4; ++mt) {
                v4f c = {0.f, 0.f, 0.f, 0.f};
                c = __builtin_amdgcn_mfma_f32_16x16x32_f16(a2[mt][0], bf2a[nt], c, 0, 0, 0);
                c = __builtin_amdgcn_mfma_f32_16x16x32_f16(a2[mt][1], bf2b[nt], c, 0, 0, 0);
#pragma unroll
                for (int e = 0; e < 4; ++e)
                    c2[mt][nt][e] = fmaxf(c[e] + bias2v[nt], 0.f);
            }

#pragma unroll
        for (int mt = 0; mt < 4; ++mt)
#pragma unroll
            for (int nt = 0; nt < 4; ++nt)
#pragma unroll
                for (int e = 0; e < 4; ++e)
                    mbuf[wid][mt * 16 + kgrp * 4 + e][nt * 16 + arow] = (_Float16)c2[mt][nt][e];

        // ---- layer 3: 64 -> 3 (padded 16), tanh, store ----
#pragma unroll
        for (int mt = 0; mt < 4; ++mt) {
            v8h a0  = *reinterpret_cast<const v8h*>(&mbuf[wid][mt * 16 + arow][kgrp * 8]);
            v8h a1v = *reinterpret_cast<const v8h*>(&mbuf[wid][mt * 16 + arow][32 + kgrp * 8]);
            v4f c = {0.f, 0.f, 0.f, 0.f};
            c = __builtin_amdgcn_mfma_f32_16x16x32_f16(a0,  bf3a, c, 0, 0, 0);
            c = __builtin_amdgcn_mfma_f32_16x16x32_f16(a1v, bf3b, c, 0, 0, 0);
            if (arow < 3) {
                float4 st;
                st.x = tanhf(c[0] + bias3);
                st.y = tanhf(c[1] + bias3);
                st.z = tanhf(c[2] + bias3);
                st.w = tanhf(c[3] + bias3);
                size_t idx = ((size_t)b * 3 + arow) * N_PIX
                           + tile * PPB + it * 256 + wid * 64 + mt * 16 + kgrp * 4;
                *reinterpret_cast<float4*>(&out[idx]) = st;
            }
        }
    }
}

extern "C" void kernel_launch(void* const* d_in, const int* in_sizes, int n_in,
                              void* d_out, int out_size, void* d_ws, size_t ws_size,
                              hipStream_t stream)
{
    const float* z  = (const float*)d_in[0];
    const float* wt = (const float*)d_in[1];
    const float* bt = (const float*)d_in[2];
    const float* w1 = (const float*)d_in[3];
    const float* b1 = (const float*)d_in[4];
    const float* w2 = (const float*)d_in[5];
    const float* b2 = (const float*)d_in[6];
    const float* w3 = (const float*)d_in[7];
    const float* b3 = (const float*)d_in[8];
    float* out  = (float*)d_out;
    float* tabs = (float*)d_ws;            // 4 MB

    ResArr ra;
    const double growth = std::exp((std::log(256.0) - std::log(16.0)) / 15.0);
    for (int l = 0; l < TABLE_NUM; ++l)
        ra.r[l] = (float)(16.0 * std::pow(growth, (double)l));

    gen_tables<<<D_TAB / 2 / 256, 256, 0, stream>>>(z, wt, bt, tabs);
    hash_mlp<<<BATCH * (N_PIX / PPB), 256, 0, stream>>>(
        tabs, w1, b1, w2, b2, w3, b3, out, ra);
}

// Round 4
// 113.343 us; speedup vs baseline: 1.2193x; 1.2193x over previous
//
#include <hip/hip_runtime.h>
#include <cmath>

#define TABLE_NUM 16
#define T_SIZE    4096
#define Z_DIM     512
#define IMG       256
#define D_TAB     (TABLE_NUM * T_SIZE * 2)       // 131072
#define BATCH     8
#define HID       64
#define N_PIX     (IMG * IMG)                    // 65536
#define PRIME_Y   2654435761u

typedef _Float16 v8h  __attribute__((ext_vector_type(8)));
typedef _Float16 v2h  __attribute__((ext_vector_type(2)));
typedef float    v4f  __attribute__((ext_vector_type(4)));

struct ResArr { float r[TABLE_NUM]; };

// ---------------------------------------------------------------------------
// Kernel 0: transpose + f16-cast MLP weights to [n][k] (MFMA B layout).
// ---------------------------------------------------------------------------
__global__ void prep_weights(const float* __restrict__ w1, const float* __restrict__ w2,
                             const float* __restrict__ w3,
                             _Float16* __restrict__ w1T, _Float16* __restrict__ w2T,
                             _Float16* __restrict__ w3T)
{
    const int t = threadIdx.x;
    for (int i = t; i < HID * 32; i += 256) {          // w1T[64][32] <- w1[32][64]
        int n = i >> 5, k = i & 31;
        w1T[i] = (_Float16)w1[k * HID + n];
    }
    for (int i = t; i < HID * HID; i += 256) {         // w2T[64][64] <- w2[64][64]
        int n = i >> 6, k = i & 63;
        w2T[i] = (_Float16)w2[k * HID + n];
    }
    for (int i = t; i < 16 * HID; i += 256) {          // w3T[16][64] <- w3[64][3], pad
        int n = i >> 6, k = i & 63;
        w3T[i] = (_Float16)(n < 3 ? w3[k * 3 + n] : 0.f);
    }
}

// ---------------------------------------------------------------------------
// Kernel 1: tables[b][n] = sum_k z[b][k]*w[k][n] + bt[n].  268 MB stream.
// 1 column/thread, 512 blocks x 256 thr -> 2 blocks/CU, 8 waves/CU.
// unroll 16 -> 32 KB in flight per CU (>= 22 KB BW*latency product).
// z reads are wave-uniform -> s_loads.
// ---------------------------------------------------------------------------
__global__ __launch_bounds__(256) void gen_tables(
    const float* __restrict__ z, const float* __restrict__ w,
    const float* __restrict__ bt, float* __restrict__ tabs)
{
    const int n = blockIdx.x * 256 + threadIdx.x;      // column 0..131071
    float acc[BATCH];
#pragma unroll
    for (int b = 0; b < BATCH; ++b) acc[b] = 0.f;

#pragma unroll 16
    for (int k = 0; k < Z_DIM; ++k) {
        float wv = w[(size_t)k * D_TAB + n];
#pragma unroll
        for (int b = 0; b < BATCH; ++b)
            acc[b] = fmaf(z[b * Z_DIM + k], wv, acc[b]);
    }

    float bv = bt[n];
#pragma unroll
    for (int b = 0; b < BATCH; ++b)
        tabs[(size_t)b * D_TAB + n] = acc[b] + bv;
}

// ---------------------------------------------------------------------------
// Kernel 2: fused hash-grid + f16-MFMA MLP.  R2 structure (36.9 KB LDS,
// ~4 blocks/CU) + 4x16 pixel tile per wave:
//   lane -> (di=lane>>4, dj=lane&15); wave covers 4 i-rows x 16 j-cols.
//   Fine-level gathers now share hash rows across lanes: ~270 distinct
//   L1 lines per wave-iter vs ~825 with the linear mapping (3x fewer
//   serialized tag lookups), at zero LDS/occupancy cost.
// Output stores stay fully coalesced: m = mt*16+kgrp*4+e -> i=i0+mt,
// j=j0+kgrp*4+e; the 4 kgrp lanes of a channel cover a full 64B row.
// mbuf is per-wave -> no __syncthreads anywhere (compiler lgkmcnt orders
// same-wave LDS deps).
// ---------------------------------------------------------------------------
__global__ __launch_bounds__(256) void hash_mlp(
    const float* __restrict__ tabs,
    const _Float16* __restrict__ w1T, const _Float16* __restrict__ w2T,
    const _Float16* __restrict__ w3T,
    const float* __restrict__ b1, const float* __restrict__ b2,
    const float* __restrict__ b3,
    float* __restrict__ out, ResArr res)
{
    __shared__ _Float16 mbuf[4][64][72];
    const int tid  = threadIdx.x;
    const int wid  = tid >> 6;
    const int lane = tid & 63;
    const int b    = blockIdx.x & 7;          // batch == XCD (round-robin)
    const int tile = blockIdx.x >> 3;         // 0..255 -> 16x16 block of pixels
    const int ti   = tile >> 4;
    const int tj   = tile & 15;
    const int i0   = ti * 16 + wid * 4;       // this wave's 4 i-rows
    const int j0   = tj * 16;                 // 16 j-cols

    const int di = lane >> 4, dj = lane & 15;
    const float cx = ((float)(i0 + di) + 0.5f) * (1.0f / IMG);
    const float cy = ((float)(j0 + dj) + 0.5f) * (1.0f / IMG);
    const float* tb = tabs + (size_t)b * D_TAB;
    const float2* tb2 = reinterpret_cast<const float2*>(tb);

    // ---- hash-grid features: 16 levels, f16 pairs straight to LDS ----
#pragma unroll 4
    for (int l = 0; l < TABLE_NUM; ++l) {
        float r  = res.r[l];
        float px = cx * r, py = cy * r;
        float fx0 = floorf(px), fy0 = floorf(py);
        float fx = px - fx0, fy = py - fy0;
        unsigned x0 = (unsigned)(int)fx0, y0 = (unsigned)(int)fy0;
        unsigned hy0 = y0 * PRIME_Y, hy1 = (y0 + 1u) * PRIME_Y;
        unsigned i00 = (x0 ^ hy0) & (T_SIZE - 1);
        unsigned i10 = ((x0 + 1u) ^ hy0) & (T_SIZE - 1);
        unsigned i01 = (x0 ^ hy1) & (T_SIZE - 1);
        unsigned i11 = ((x0 + 1u) ^ hy1) & (T_SIZE - 1);
        const float2* tl = tb2 + l * T_SIZE;
        float2 f00 = tl[i00], f10 = tl[i10], f01 = tl[i01], f11 = tl[i11];
        float w00 = (1.f - fx) * (1.f - fy);
        float w10 = fx * (1.f - fy);
        float w01 = (1.f - fx) * fy;
        float w11 = fx * fy;
        float e0 = f00.x * w00 + f10.x * w10 + f01.x * w01 + f11.x * w11;
        float e1 = f00.y * w00 + f10.y * w10 + f01.y * w01 + f11.y * w11;
        v2h p; p.x = (_Float16)e0; p.y = (_Float16)e1;
        *reinterpret_cast<v2h*>(&mbuf[wid][lane][2 * l]) = p;
    }

    const int arow = lane & 15;        // A row / B col / C col
    const int kgrp = lane >> 4;        // k-group

    float bias1v[4], bias2v[4];
#pragma unroll
    for (int nt = 0; nt < 4; ++nt) {
        bias1v[nt] = b1[nt * 16 + arow];
        bias2v[nt] = b2[nt * 16 + arow];
    }
    const float bias3 = (arow < 3) ? b3[arow] : 0.f;

    v8h bf1[4], bf2a[4], bf2b[4];
#pragma unroll
    for (int nt = 0; nt < 4; ++nt) {
        bf1[nt]  = *reinterpret_cast<const v8h*>(&w1T[(nt * 16 + arow) * 32 + kgrp * 8]);
        bf2a[nt] = *reinterpret_cast<const v8h*>(&w2T[(nt * 16 + arow) * 64 + kgrp * 8]);
        bf2b[nt] = *reinterpret_cast<const v8h*>(&w2T[(nt * 16 + arow) * 64 + 32 + kgrp * 8]);
    }
    v8h bf3a = *reinterpret_cast<const v8h*>(&w3T[arow * 64 + kgrp * 8]);
    v8h bf3b = *reinterpret_cast<const v8h*>(&w3T[arow * 64 + 32 + kgrp * 8]);

    // ---- layer 1: 32 -> 64 ----
    v8h a1[4];
#pragma unroll
    for (int mt = 0; mt < 4; ++mt)
        a1[mt] = *reinterpret_cast<const v8h*>(&mbuf[wid][mt * 16 + arow][kgrp * 8]);

    v4f c1[4][4];
#pragma unroll
    for (int nt = 0; nt < 4; ++nt)
#pragma unroll
        for (int mt = 0; mt < 4; ++mt) {
            v4f c = {0.f, 0.f, 0.f, 0.f};
            c = __builtin_amdgcn_mfma_f32_16x16x32_f16(a1[mt], bf1[nt], c, 0, 0, 0);
#pragma unroll
            for (int e = 0; e < 4; ++e)
                c1[mt][nt][e] = fmaxf(c[e] + bias1v[nt], 0.f);
        }

#pragma unroll
    for (int mt = 0; mt < 4; ++mt)
#pragma unroll
        for (int nt = 0; nt < 4; ++nt)
#pragma unroll
            for (int e = 0; e < 4; ++e)
                mbuf[wid][mt * 16 + kgrp * 4 + e][nt * 16 + arow] = (_Float16)c1[mt][nt][e];

    // ---- layer 2: 64 -> 64 ----
    v8h a2[4][2];
#pragma unroll
    for (int mt = 0; mt < 4; ++mt) {
        a2[mt][0] = *reinterpret_cast<const v8h*>(&mbuf[wid][mt * 16 + arow][kgrp * 8]);
        a2[mt][1] = *reinterpret_cast<const v8h*>(&mbuf[wid][mt * 16 + arow][32 + kgrp * 8]);
    }
    v4f c2[4][4];
#pragma unroll
    for (int nt = 0; nt < 4; ++nt)
#pragma unroll
        for (int mt = 0; mt < 4; ++mt) {
            v4f c = {0.f, 0.f, 0.f, 0.f};
            c = __builtin_amdgcn_mfma_f32_16x16x32_f16(a2[mt][0], bf2a[nt], c, 0, 0, 0);
            c = __builtin_amdgcn_mfma_f32_16x16x32_f16(a2[mt][1], bf2b[nt], c, 0, 0, 0);
#pragma unroll
            for (int e = 0; e < 4; ++e)
                c2[mt][nt][e] = fmaxf(c[e] + bias2v[nt], 0.f);
        }

#pragma unroll
    for (int mt = 0; mt < 4; ++mt)
#pragma unroll
        for (int nt = 0; nt < 4; ++nt)
#pragma unroll
            for (int e = 0; e < 4; ++e)
                mbuf[wid][mt * 16 + kgrp * 4 + e][nt * 16 + arow] = (_Float16)c2[mt][nt][e];

    // ---- layer 3: 64 -> 3 (padded 16), tanh, coalesced row stores ----
#pragma unroll
    for (int mt = 0; mt < 4; ++mt) {
        v8h a0  = *reinterpret_cast<const v8h*>(&mbuf[wid][mt * 16 + arow][kgrp * 8]);
        v8h a1v = *reinterpret_cast<const v8h*>(&mbuf[wid][mt * 16 + arow][32 + kgrp * 8]);
        v4f c = {0.f, 0.f, 0.f, 0.f};
        c = __builtin_amdgcn_mfma_f32_16x16x32_f16(a0,  bf3a, c, 0, 0, 0);
        c = __builtin_amdgcn_mfma_f32_16x16x32_f16(a1v, bf3b, c, 0, 0, 0);
        if (arow < 3) {
            float4 st;
            st.x = tanhf(c[0] + bias3);
            st.y = tanhf(c[1] + bias3);
            st.z = tanhf(c[2] + bias3);
            st.w = tanhf(c[3] + bias3);
            // pixel m = mt*16 + kgrp*4 + e  ->  i = i0+mt, j = j0+kgrp*4+e
            size_t idx = ((size_t)b * 3 + arow) * N_PIX
                       + (size_t)(i0 + mt) * IMG + j0 + kgrp * 4;
            *reinterpret_cast<float4*>(&out[idx]) = st;
        }
    }
}

extern "C" void kernel_launch(void* const* d_in, const int* in_sizes, int n_in,
                              void* d_out, int out_size, void* d_ws, size_t ws_size,
                              hipStream_t stream)
{
    const float* z  = (const float*)d_in[0];
    const float* wt = (const float*)d_in[1];
    const float* bt = (const float*)d_in[2];
    const float* w1 = (const float*)d_in[3];
    const float* b1 = (const float*)d_in[4];
    const float* w2 = (const float*)d_in[5];
    const float* b2 = (const float*)d_in[6];
    const float* w3 = (const float*)d_in[7];
    const float* b3 = (const float*)d_in[8];
    float* out  = (float*)d_out;

    char* ws = (char*)d_ws;
    float*     tabs = (float*)ws;                          // 4 MB
    _Float16*  w1T  = (_Float16*)(ws + (4 << 20));         // 4 KB
    _Float16*  w2T  = (_Float16*)(ws + (4 << 20) + 4096);  // 8 KB
    _Float16*  w3T  = (_Float16*)(ws + (4 << 20) + 12288); // 2 KB

    ResArr ra;
    const double growth = std::exp((std::log(256.0) - std::log(16.0)) / 15.0);
    for (int l = 0; l < TABLE_NUM; ++l)
        ra.r[l] = (float)(16.0 * std::pow(growth, (double)l));

    prep_weights<<<1, 256, 0, stream>>>(w1, w2, w3, w1T, w2T, w3T);
    gen_tables<<<D_TAB / 256, 256, 0, stream>>>(z, wt, bt, tabs);
    hash_mlp<<<BATCH * (N_PIX / 256), 256, 0, stream>>>(
        tabs, w1T, w2T, w3T, b1, b2, b3, out, ra);
}